// Round 1
// baseline (750.238 us; speedup 1.0000x reference)
//
#include <hip/hip_runtime.h>
#include <math.h>

// energies[b,i,j] = out_state[b,i,:] . (W @ history[b,j,:] + bias); out = softmax_j.
// Restructured:
//   q[b,i,:] = W^T @ out_state[b,i,:]   (project small side; bias cancels in softmax)
//   E[b,i,j] = q[b,i,:] . history[b,j,:]
// Precision: fp32 operands split into bf16 hi+lo; x.y ~= xh.yh + xh.yl + xl.yh
// via MFMA 16x16x32 bf16 with fp32 accumulate (error ~2^-16 rel, threshold 2e-2).
// R2: split fused into GEMM LDS staging (truncation split, v_perm packing) —
// eliminates both standalone split_f32 kernels (~670 MB HBM). XCD-aware block
// swizzle on both GEMMs for per-XCD L2 batch locality.
constexpr int B        = 64;
constexpr int S_STATE  = 512;
constexpr int S_SEQ    = 2048;
constexpr int H        = 512;

typedef __attribute__((ext_vector_type(8))) short bf16x8;
typedef __attribute__((ext_vector_type(4))) float f32x4;

static __device__ __forceinline__ unsigned short f2bf(float f) {
    unsigned int u = __float_as_uint(f);
    u = u + 0x7FFFu + ((u >> 16) & 1u);   // RNE
    return (unsigned short)(u >> 16);
}
static __device__ __forceinline__ float bf2f(unsigned short h) {
    return __uint_as_float(((unsigned int)h) << 16);
}

// pack_hi16(b0,b1): low16 = b0>>16, high16 = b1>>16 (one v_perm_b32)
static __device__ __forceinline__ unsigned pack_hi16(unsigned b0, unsigned b1) {
    return __builtin_amdgcn_perm(b1, b0, 0x07060302u);
}

// Truncation split of 8 fp32 -> 8 bf16 hi + 8 bf16 lo (packed as uint4 each).
// hi = top 16 bits (round-toward-zero); rest = x - hi is EXACT; lo = trunc(rest).
// |x - hi - lo| <= 2^-16 |x|; dropped lo*lo MFMA term ~2^-16 — both negligible
// vs the 2e-2 output threshold.
static __device__ __forceinline__ void split8(const float4 x, const float4 y,
                                              uint4& hi, uint4& lo) {
    const unsigned b0 = __float_as_uint(x.x), b1 = __float_as_uint(x.y);
    const unsigned b2 = __float_as_uint(x.z), b3 = __float_as_uint(x.w);
    const unsigned b4 = __float_as_uint(y.x), b5 = __float_as_uint(y.y);
    const unsigned b6 = __float_as_uint(y.z), b7 = __float_as_uint(y.w);
    hi.x = pack_hi16(b0, b1);
    hi.y = pack_hi16(b2, b3);
    hi.z = pack_hi16(b4, b5);
    hi.w = pack_hi16(b6, b7);
    const float r0 = x.x - __uint_as_float(b0 & 0xFFFF0000u);
    const float r1 = x.y - __uint_as_float(b1 & 0xFFFF0000u);
    const float r2 = x.z - __uint_as_float(b2 & 0xFFFF0000u);
    const float r3 = x.w - __uint_as_float(b3 & 0xFFFF0000u);
    const float r4 = y.x - __uint_as_float(b4 & 0xFFFF0000u);
    const float r5 = y.y - __uint_as_float(b5 & 0xFFFF0000u);
    const float r6 = y.z - __uint_as_float(b6 & 0xFFFF0000u);
    const float r7 = y.w - __uint_as_float(b7 & 0xFFFF0000u);
    lo.x = pack_hi16(__float_as_uint(r0), __float_as_uint(r1));
    lo.y = pack_hi16(__float_as_uint(r2), __float_as_uint(r3));
    lo.z = pack_hi16(__float_as_uint(r4), __float_as_uint(r5));
    lo.w = pack_hi16(__float_as_uint(r6), __float_as_uint(r7));
}

// W[h][d] -> Wt_hi/lo[d][h]  (512x512, tiny; RNE split, paid once)
__global__ __launch_bounds__(256) void split_transpose_w(const float* __restrict__ w,
                                                         unsigned short* __restrict__ thi,
                                                         unsigned short* __restrict__ tlo) {
    int idx = blockIdx.x * 256 + threadIdx.x;     // h*512 + d, d fastest
    int h = idx >> 9, d = idx & 511;
    float v = w[idx];
    unsigned short hh = f2bf(v);
    thi[d * 512 + h] = hh;
    tlo[d * 512 + h] = f2bf(v - bf2f(hh));
}

// ---------------------------------------------------------------------------
// Batched NT GEMM, split-bf16 MFMA:  C[m][n] = sum_k A[m][k] * B[n][k]
// A/B either fp32 (split fused into staging) or pre-split bf16 hi/lo pairs,
// K-contiguous rows. BM=BN=128, BK=32, 256 threads = 4 waves, each wave a
// 64x64 quadrant = 4x4 MFMA 16x16 tiles. SPLIT_OUT: write C as bf16 hi/lo.
// XCD-aware bijective block swizzle: each of the 8 XCDs gets a contiguous
// chunk of the linearized grid (batch-contiguous) for per-XCD L2 locality.
// ---------------------------------------------------------------------------
constexpr int LP = 40;   // LDS row pitch (elements); 80B stride -> 2-way banks max

template <bool A_F32, bool B_F32, bool SPLIT_OUT>
__global__ __launch_bounds__(256)
void gemm_nt_mfma(const float* __restrict__ Af,
                  const unsigned short* __restrict__ Ahi, const unsigned short* __restrict__ Alo,
                  const float* __restrict__ Bf,
                  const unsigned short* __restrict__ Bhi, const unsigned short* __restrict__ Blo,
                  float* __restrict__ Cf, unsigned short* __restrict__ Chi,
                  unsigned short* __restrict__ Clo,
                  int K, int N, size_t aBatch, size_t bBatch, size_t cBatch) {
    __shared__ unsigned short sA[2][128 * LP];   // [hi/lo][row*LP + k]
    __shared__ unsigned short sB[2][128 * LP];

    const int t = threadIdx.x;

    // XCD swizzle: linear id -> chunk-per-XCD bijection (requires total%8==0)
    unsigned bx = blockIdx.x, by = blockIdx.y, bz = blockIdx.z;
    {
        const unsigned gx = gridDim.x, gxy = gridDim.x * gridDim.y;
        const unsigned total = gxy * gridDim.z;
        if ((total & 7u) == 0u) {
            const unsigned lid = bx + gx * by + gxy * bz;
            const unsigned swz = (lid & 7u) * (total >> 3) + (lid >> 3);
            bz = swz / gxy;
            const unsigned rem = swz - bz * gxy;
            by = rem / gx;
            bx = rem - by * gx;
        }
    }

    const int m0 = by * 128;
    const int n0 = bx * 128;
    const size_t aOff = (size_t)bz * aBatch;
    const size_t bOff = (size_t)bz * bBatch;
    const size_t cOff = (size_t)bz * cBatch;

    const int lane = t & 63, wv = t >> 6;
    const int wm = wv >> 1, wn = wv & 1;
    const int lrow = lane & 15, quad = lane >> 4;
    const int fko = quad * 8;                    // frag k-offset (8 bf16 = 16B)

    // staging: thread t covers rows r0 and r0+64, k-offset kk (8 elements = 16B bf16)
    const int r0 = t >> 2;                       // 0..63
    const int kk = (t & 3) * 8;                  // 0,8,16,24

    f32x4 acc[4][4];
#pragma unroll
    for (int i = 0; i < 4; ++i)
#pragma unroll
        for (int j = 0; j < 4; ++j) acc[i][j] = (f32x4){0.f, 0.f, 0.f, 0.f};

    for (int k0 = 0; k0 < K; k0 += 32) {
        uint4 vAh0, vAh1, vAl0, vAl1, vBh0, vBh1, vBl0, vBl1;
        {
            const size_t ga0 = aOff + (size_t)(m0 + r0) * K + k0 + kk;
            const size_t ga1 = ga0 + (size_t)64 * K;
            if constexpr (A_F32) {
                const float4 x0 = *reinterpret_cast<const float4*>(&Af[ga0]);
                const float4 x1 = *reinterpret_cast<const float4*>(&Af[ga0 + 4]);
                const float4 y0 = *reinterpret_cast<const float4*>(&Af[ga1]);
                const float4 y1 = *reinterpret_cast<const float4*>(&Af[ga1 + 4]);
                split8(x0, x1, vAh0, vAl0);
                split8(y0, y1, vAh1, vAl1);
            } else {
                vAh0 = *reinterpret_cast<const uint4*>(&Ahi[ga0]);
                vAh1 = *reinterpret_cast<const uint4*>(&Ahi[ga1]);
                vAl0 = *reinterpret_cast<const uint4*>(&Alo[ga0]);
                vAl1 = *reinterpret_cast<const uint4*>(&Alo[ga1]);
            }
        }
        {
            const size_t gb0 = bOff + (size_t)(n0 + r0) * K + k0 + kk;
            const size_t gb1 = gb0 + (size_t)64 * K;
            if constexpr (B_F32) {
                const float4 x0 = *reinterpret_cast<const float4*>(&Bf[gb0]);
                const float4 x1 = *reinterpret_cast<const float4*>(&Bf[gb0 + 4]);
                const float4 y0 = *reinterpret_cast<const float4*>(&Bf[gb1]);
                const float4 y1 = *reinterpret_cast<const float4*>(&Bf[gb1 + 4]);
                split8(x0, x1, vBh0, vBl0);
                split8(y0, y1, vBh1, vBl1);
            } else {
                vBh0 = *reinterpret_cast<const uint4*>(&Bhi[gb0]);
                vBh1 = *reinterpret_cast<const uint4*>(&Bhi[gb1]);
                vBl0 = *reinterpret_cast<const uint4*>(&Blo[gb0]);
                vBl1 = *reinterpret_cast<const uint4*>(&Blo[gb1]);
            }
        }

        __syncthreads();   // previous iteration's frag reads complete
        const int s0 = r0 * LP + kk, s1 = (r0 + 64) * LP + kk;
        *reinterpret_cast<uint4*>(&sA[0][s0]) = vAh0;
        *reinterpret_cast<uint4*>(&sA[0][s1]) = vAh1;
        *reinterpret_cast<uint4*>(&sA[1][s0]) = vAl0;
        *reinterpret_cast<uint4*>(&sA[1][s1]) = vAl1;
        *reinterpret_cast<uint4*>(&sB[0][s0]) = vBh0;
        *reinterpret_cast<uint4*>(&sB[0][s1]) = vBh1;
        *reinterpret_cast<uint4*>(&sB[1][s0]) = vBl0;
        *reinterpret_cast<uint4*>(&sB[1][s1]) = vBl1;
        __syncthreads();

        bf16x8 aH[4], aL[4];
#pragma unroll
        for (int mt = 0; mt < 4; ++mt) {
            const int r = (wm * 64 + mt * 16 + lrow) * LP + fko;
            aH[mt] = *reinterpret_cast<const bf16x8*>(&sA[0][r]);
            aL[mt] = *reinterpret_cast<const bf16x8*>(&sA[1][r]);
        }
#pragma unroll
        for (int nt = 0; nt < 4; ++nt) {
            const int r = (wn * 64 + nt * 16 + lrow) * LP + fko;
            const bf16x8 bH = *reinterpret_cast<const bf16x8*>(&sB[0][r]);
            const bf16x8 bL = *reinterpret_cast<const bf16x8*>(&sB[1][r]);
#pragma unroll
            for (int mt = 0; mt < 4; ++mt) {
                acc[mt][nt] = __builtin_amdgcn_mfma_f32_16x16x32_bf16(aH[mt], bH, acc[mt][nt], 0, 0, 0);
                acc[mt][nt] = __builtin_amdgcn_mfma_f32_16x16x32_bf16(aH[mt], bL, acc[mt][nt], 0, 0, 0);
                acc[mt][nt] = __builtin_amdgcn_mfma_f32_16x16x32_bf16(aL[mt], bH, acc[mt][nt], 0, 0, 0);
            }
        }
    }

    // epilogue: C/D layout col=lane&15, row=quad*4+reg (verified m89/m91)
#pragma unroll
    for (int mt = 0; mt < 4; ++mt) {
#pragma unroll
        for (int nt = 0; nt < 4; ++nt) {
#pragma unroll
            for (int r = 0; r < 4; ++r) {
                const int gi = m0 + wm * 64 + mt * 16 + quad * 4 + r;
                const int gj = n0 + wn * 64 + nt * 16 + lrow;
                const float v = acc[mt][nt][r];
                if constexpr (SPLIT_OUT) {
                    const unsigned short hh = f2bf(v);
                    Chi[cOff + (size_t)gi * N + gj] = hh;
                    Clo[cOff + (size_t)gi * N + gj] = f2bf(v - bf2f(hh));
                } else {
                    Cf[cOff + (size_t)gi * N + gj] = v;
                }
            }
        }
    }
}

// ---------------------------------------------------------------------------
// Softmax over rows of 2048, in place. One 256-thread block per row.
// ---------------------------------------------------------------------------
__global__ __launch_bounds__(256) void softmax_rows(float* __restrict__ out) {
    const int t = threadIdx.x;
    const size_t base = (size_t)blockIdx.x * S_SEQ;

    float4 v0 = *reinterpret_cast<float4*>(&out[base + (t << 2)]);
    float4 v1 = *reinterpret_cast<float4*>(&out[base + 1024 + (t << 2)]);

    float m = fmaxf(fmaxf(fmaxf(v0.x, v0.y), fmaxf(v0.z, v0.w)),
                    fmaxf(fmaxf(v1.x, v1.y), fmaxf(v1.z, v1.w)));
#pragma unroll
    for (int off = 32; off; off >>= 1) m = fmaxf(m, __shfl_xor(m, off));

    __shared__ float redm[4];
    __shared__ float reds[4];
    if ((t & 63) == 0) redm[t >> 6] = m;
    __syncthreads();
    m = fmaxf(fmaxf(redm[0], redm[1]), fmaxf(redm[2], redm[3]));

    v0.x = __expf(v0.x - m); v0.y = __expf(v0.y - m);
    v0.z = __expf(v0.z - m); v0.w = __expf(v0.w - m);
    v1.x = __expf(v1.x - m); v1.y = __expf(v1.y - m);
    v1.z = __expf(v1.z - m); v1.w = __expf(v1.w - m);

    float s = v0.x + v0.y + v0.z + v0.w + v1.x + v1.y + v1.z + v1.w;
#pragma unroll
    for (int off = 32; off; off >>= 1) s += __shfl_xor(s, off);
    if ((t & 63) == 0) reds[t >> 6] = s;
    __syncthreads();
    s = reds[0] + reds[1] + reds[2] + reds[3];

    const float inv = 1.0f / s;
    v0.x *= inv; v0.y *= inv; v0.z *= inv; v0.w *= inv;
    v1.x *= inv; v1.y *= inv; v1.z *= inv; v1.w *= inv;

    *reinterpret_cast<float4*>(&out[base + (t << 2)]) = v0;
    *reinterpret_cast<float4*>(&out[base + 1024 + (t << 2)]) = v1;
}

// ===========================================================================
// fp32 fallback path (round-1 kernels) used only if ws_size is too small.
// ===========================================================================
__global__ __launch_bounds__(256) void gemm_nn(const float* __restrict__ A,
                                               const float* __restrict__ Bg,
                                               float* __restrict__ C) {
    constexpr int K = H, N = H;
    __shared__ float As[32][68];
    __shared__ float Bs[32][68];
    const int t  = threadIdx.x;
    const int m0 = blockIdx.y * 64;
    const int n0 = blockIdx.x * 64;
    const int aK = (t & 7) << 2;
    const int aR = t >> 3;
    const int bN = (t & 15) << 2;
    const int bK = t >> 4;
    const int tx = t & 15;
    const int ty = t >> 4;
    float acc[4][4];
#pragma unroll
    for (int i = 0; i < 4; ++i)
#pragma unroll
        for (int j = 0; j < 4; ++j) acc[i][j] = 0.f;
    for (int k0 = 0; k0 < K; k0 += 32) {
#pragma unroll
        for (int r = 0; r < 2; ++r) {
            const int row = aR + 32 * r;
            const float4 v = *reinterpret_cast<const float4*>(&A[(size_t)(m0 + row) * K + k0 + aK]);
            As[aK + 0][row] = v.x; As[aK + 1][row] = v.y;
            As[aK + 2][row] = v.z; As[aK + 3][row] = v.w;
        }
#pragma unroll
        for (int r = 0; r < 2; ++r) {
            const int kkk = bK + 16 * r;
            *reinterpret_cast<float4*>(&Bs[kkk][bN]) =
                *reinterpret_cast<const float4*>(&Bg[(size_t)(k0 + kkk) * N + n0 + bN]);
        }
        __syncthreads();
#pragma unroll
        for (int kkk = 0; kkk < 32; ++kkk) {
            const float4 av = *reinterpret_cast<const float4*>(&As[kkk][ty << 2]);
            const float4 bv = *reinterpret_cast<const float4*>(&Bs[kkk][tx << 2]);
            const float a[4] = {av.x, av.y, av.z, av.w};
            const float b[4] = {bv.x, bv.y, bv.z, bv.w};
#pragma unroll
            for (int i = 0; i < 4; ++i)
#pragma unroll
                for (int j = 0; j < 4; ++j) acc[i][j] += a[i] * b[j];
        }
        __syncthreads();
    }
#pragma unroll
    for (int i = 0; i < 4; ++i) {
        float4 v = make_float4(acc[i][0], acc[i][1], acc[i][2], acc[i][3]);
        *reinterpret_cast<float4*>(&C[(size_t)(m0 + (ty << 2) + i) * N + n0 + (tx << 2)]) = v;
    }
}

__global__ __launch_bounds__(256) void gemm_nt_batched(const float* __restrict__ Q,
                                                       const float* __restrict__ Hist,
                                                       float* __restrict__ E) {
    constexpr int K = H;
    __shared__ float As[32][68];
    __shared__ float Bs[32][68];
    const int t  = threadIdx.x;
    const int m0 = blockIdx.y * 64;
    const int n0 = blockIdx.x * 64;
    const int b  = blockIdx.z;
    const float* Qb = Q    + (size_t)b * S_STATE * H;
    const float* Hb = Hist + (size_t)b * S_SEQ   * H;
    float*       Eb = E    + (size_t)b * S_STATE * S_SEQ;
    const int aK = (t & 7) << 2;
    const int aR = t >> 3;
    const int tx = t & 15;
    const int ty = t >> 4;
    float acc[4][4];
#pragma unroll
    for (int i = 0; i < 4; ++i)
#pragma unroll
        for (int j = 0; j < 4; ++j) acc[i][j] = 0.f;
    for (int k0 = 0; k0 < K; k0 += 32) {
#pragma unroll
        for (int r = 0; r < 2; ++r) {
            const int row = aR + 32 * r;
            const float4 v = *reinterpret_cast<const float4*>(&Qb[(size_t)(m0 + row) * K + k0 + aK]);
            As[aK + 0][row] = v.x; As[aK + 1][row] = v.y;
            As[aK + 2][row] = v.z; As[aK + 3][row] = v.w;
        }
#pragma unroll
        for (int r = 0; r < 2; ++r) {
            const int row = aR + 32 * r;
            const float4 v = *reinterpret_cast<const float4*>(&Hb[(size_t)(n0 + row) * K + k0 + aK]);
            Bs[aK + 0][row] = v.x; Bs[aK + 1][row] = v.y;
            Bs[aK + 2][row] = v.z; Bs[aK + 3][row] = v.w;
        }
        __syncthreads();
#pragma unroll
        for (int kkk = 0; kkk < 32; ++kkk) {
            const float4 av = *reinterpret_cast<const float4*>(&As[kkk][ty << 2]);
            const float4 bv = *reinterpret_cast<const float4*>(&Bs[kkk][tx << 2]);
            const float a[4] = {av.x, av.y, av.z, av.w};
            const float b2[4] = {bv.x, bv.y, bv.z, bv.w};
#pragma unroll
            for (int i = 0; i < 4; ++i)
#pragma unroll
                for (int j = 0; j < 4; ++j) acc[i][j] += a[i] * b2[j];
        }
        __syncthreads();
    }
#pragma unroll
    for (int i = 0; i < 4; ++i) {
        float4 v = make_float4(acc[i][0], acc[i][1], acc[i][2], acc[i][3]);
        *reinterpret_cast<float4*>(&Eb[(size_t)(m0 + (ty << 2) + i) * S_SEQ + n0 + (tx << 2)]) = v;
    }
}

// ===========================================================================
extern "C" void kernel_launch(void* const* d_in, const int* in_sizes, int n_in,
                              void* d_out, int out_size, void* d_ws, size_t ws_size,
                              hipStream_t stream) {
    const float* out_state = (const float*)d_in[0]; // [B, S_STATE, H]
    const float* history   = (const float*)d_in[1]; // [B, S_SEQ, H]
    const float* attn_w    = (const float*)d_in[2]; // [H, H]
    // attn_b (d_in[3]) unused: constant along softmax axis -> cancels exactly.
    float* out = (float*)d_out;

    // ws partition (bf16 split arrays), 256B aligned. Only W^T and q are
    // materialized split now; out_state/history split is fused into staging.
    const size_t nOS = (size_t)B * S_STATE * H;      // 16.7M
    const size_t nW  = (size_t)H * H;
    size_t off = 0;
    auto alloc = [&](size_t bytes) { size_t o = off; off = (off + bytes + 255) & ~(size_t)255; return o; };
    char* ws = (char*)d_ws;
    const size_t o_wth = alloc(nW * 2),  o_wtl = alloc(nW * 2);
    const size_t o_qh  = alloc(nOS * 2), o_ql  = alloc(nOS * 2);
    const size_t need = off;

    if (ws_size >= need) {
        unsigned short* wt_h = (unsigned short*)(ws + o_wth);
        unsigned short* wt_l = (unsigned short*)(ws + o_wtl);
        unsigned short* q_h  = (unsigned short*)(ws + o_qh);
        unsigned short* q_l  = (unsigned short*)(ws + o_ql);

        split_transpose_w<<<(int)(nW / 256), 256, 0, stream>>>(attn_w, wt_h, wt_l);

        // q[m][d] = sum_k os[m][k] * Wt[d][k]   (M=32768, N=512, K=512)
        // A = out_state fp32 (split fused), B = Wt pre-split, C = q split-out
        gemm_nt_mfma<true, false, true><<<dim3(H / 128, (B * S_STATE) / 128, 1), 256, 0, stream>>>(
            out_state, nullptr, nullptr, nullptr, wt_h, wt_l,
            nullptr, q_h, q_l, H, H, 0, 0, 0);

        // E[b][i][j] = sum_k q[b][i][k] * hist[b][j][k]
        // A = q pre-split, B = history fp32 (split fused), C = E fp32
        gemm_nt_mfma<false, true, false><<<dim3(S_SEQ / 128, S_STATE / 128, B), 256, 0, stream>>>(
            nullptr, q_h, q_l, history, nullptr, nullptr,
            out, nullptr, nullptr, H, S_SEQ,
            (size_t)S_STATE * H, (size_t)S_SEQ * H, (size_t)S_STATE * S_SEQ);

        softmax_rows<<<B * S_STATE, 256, 0, stream>>>(out);
    } else {
        // fp32 fallback (round-1 path), needs 64 MiB ws
        float* q = (float*)d_ws;
        gemm_nn<<<dim3(H / 64, (B * S_STATE) / 64), 256, 0, stream>>>(out_state, attn_w, q);
        gemm_nt_batched<<<dim3(S_SEQ / 64, S_STATE / 64, B), 256, 0, stream>>>(q, history, out);
        softmax_rows<<<B * S_STATE, 256, 0, stream>>>(out);
    }
}